// Round 5
// baseline (91.522 us; speedup 1.0000x reference)
//
#include <hip/hip_runtime.h>

// out[c,b,g] = sum_{s<8} prod_{l<3} x[b, I[c,g,s,l]]
#define Cc 16
#define Gg 8192
#define Ss 8
#define Ll 3
#define Bb 32

#define SLICES 16          // b-pair slices: slice z holds b = 2z, 2z+1
#define THREADS 512        // one thread per (c,g); 256 blocks total

// --- async global->LDS, 16 B per lane. LDS dest must be wave-uniform base;
// HW scatters lane i at base + i*16 (CK-style address-space casts).
__device__ __forceinline__ void async_load16(const void* gsrc, void* lds) {
    uint32_t l32 = (uint32_t)__builtin_amdgcn_readfirstlane((uint32_t)(uintptr_t)lds);
    __builtin_amdgcn_global_load_lds(
        (const __attribute__((address_space(1))) uint32_t*)(uintptr_t)gsrc,
        (__attribute__((address_space(3))) uint32_t*)(uintptr_t)l32,
        16, 0, 0);
}

// Stage one 64 KB slice (G float2s) into LDS: 8 waves x 8 calls x 1 KB.
__device__ __forceinline__ void stage_slice(const float2* gsrc, float2* ldst, int tid) {
    const char* g = (const char*)gsrc;
    char* l = (char*)ldst;
    const int lane = tid & 63;
    const int w = tid >> 6;                  // 0..7, wave-uniform
    #pragma unroll
    for (int i = 0; i < 8; ++i) {
        int off = ((i << 3) | w) << 10;      // (i*8+w)*1024 bytes
        async_load16(g + off + lane * 16, l + off);
    }
}

// --- Kernel 1: pairs-major layout xs[z][g] = {x[2z][g], x[2z+1][g]}. 1 MB.
__global__ __launch_bounds__(256) void build_xpairs(const float* __restrict__ x,
                                                    float2* __restrict__ xs) {
    int t = blockIdx.x * 256 + threadIdx.x;
    int z = t >> 13;
    int g = t & (Gg - 1);
    float a = x[(size_t)(2 * z) * Gg + g];
    float b = x[(size_t)(2 * z + 1) * Gg + g];
    xs[t] = make_float2(a, b);
}

// --- Kernel 2: one thread per (c,g). Indices live in VGPRs for the whole
// kernel (read ONCE: 12 MB total, vs 192 MB in the per-slice-grid version).
// Block loops over the 16 b-pair slices, double-buffered async restaging.
__global__ __launch_bounds__(THREADS) void clause_all(const float2* __restrict__ xs,
                                                      const int* __restrict__ I,
                                                      float* __restrict__ out) {
    __shared__ float2 buf[2 * Gg];           // 2 x 64 KB
    const int tid = threadIdx.x;
    const int flat = blockIdx.x * THREADS + tid;
    const int c = flat >> 13;                // block-uniform (8192 g per c)
    const int g = flat & (Gg - 1);           // 64 consecutive g per wave

    // Prologue: stage slice 0; index loads overlap the staging.
    stage_slice(xs, buf, tid);

    const int4* I4 = (const int4*)(I + ((size_t)c * Gg + g) * (Ss * Ll));
    int4 q0 = I4[0], q1 = I4[1], q2 = I4[2], q3 = I4[3], q4 = I4[4], q5 = I4[5];
    int idx[Ss * Ll] = {q0.x, q0.y, q0.z, q0.w, q1.x, q1.y, q1.z, q1.w,
                        q2.x, q2.y, q2.z, q2.w, q3.x, q3.y, q3.z, q3.w,
                        q4.x, q4.y, q4.z, q4.w, q5.x, q5.y, q5.z, q5.w};

    float* op = out + ((size_t)(c * Bb)) * Gg + g;   // row b=0 for this (c,g)

    #pragma unroll 1
    for (int z = 0; z < SLICES; ++z) {
        // Barrier drains vmcnt(0): slice z staged; also all waves done
        // gathering slice z-1, so its buffer may be overwritten below.
        __syncthreads();
        float2* cur = buf + (z & 1) * Gg;
        if (z + 1 < SLICES)
            stage_slice(xs + (size_t)(z + 1) * Gg, buf + ((z + 1) & 1) * Gg, tid);

        // 24 independent random ds_read_b64 gathers.
        float2 v[Ss * Ll];
        #pragma unroll
        for (int k = 0; k < Ss * Ll; ++k)
            v[k] = cur[idx[k]];

        float2 s = {0.f, 0.f};
        #pragma unroll
        for (int q = 0; q < Ss; ++q) {
            s.x += v[3 * q].x * v[3 * q + 1].x * v[3 * q + 2].x;
            s.y += v[3 * q].y * v[3 * q + 1].y * v[3 * q + 2].y;
        }

        // b = 2z, 2z+1; lanes span 64 consecutive g -> 256 B coalesced runs.
        op[(size_t)(2 * z) * Gg] = s.x;
        op[(size_t)(2 * z + 1) * Gg] = s.y;
    }
}

// --- Fallback (no workspace): gather directly from x (B,G); slow but correct.
__global__ __launch_bounds__(256) void clause_kernel_direct(const float* __restrict__ x,
                                                            const int* __restrict__ I,
                                                            float* __restrict__ out) {
    const int tid = threadIdx.x;
    const int b = tid & 31;
    const int j = tid >> 5;
    const int g = blockIdx.x * 8 + j;
    const int c = blockIdx.y;

    const int* Icg = I + (size_t)(c * Gg + g) * (Ss * Ll);
    float sum = 0.f;
    #pragma unroll
    for (int s = 0; s < Ss; ++s) {
        float p0 = x[(size_t)b * Gg + Icg[3 * s + 0]];
        float p1 = x[(size_t)b * Gg + Icg[3 * s + 1]];
        float p2 = x[(size_t)b * Gg + Icg[3 * s + 2]];
        sum += p0 * p1 * p2;
    }
    out[(size_t)(c * Bb + b) * Gg + g] = sum;
}

extern "C" void kernel_launch(void* const* d_in, const int* in_sizes, int n_in,
                              void* d_out, int out_size, void* d_ws, size_t ws_size,
                              hipStream_t stream) {
    const float* x = (const float*)d_in[0];
    const int* I = (const int*)d_in[1];
    float* out = (float*)d_out;

    const size_t xs_bytes = (size_t)SLICES * Gg * sizeof(float2);  // 1 MB

    if (ws_size >= xs_bytes) {
        float2* xs = (float2*)d_ws;
        build_xpairs<<<(SLICES * Gg) / 256, 256, 0, stream>>>(x, xs);
        clause_all<<<(Cc * Gg) / THREADS, THREADS, 0, stream>>>(xs, I, out);
    } else {
        clause_kernel_direct<<<dim3(Gg / 8, Cc), 256, 0, stream>>>(x, I, out);
    }
}

// Round 6
// 89.772 us; speedup vs baseline: 1.0195x; 1.0195x over previous
//
#include <hip/hip_runtime.h>
#include <stdint.h>

// out[c,b,g] = sum_{s<8} prod_{l<3} x[b, I[c,g,s,l]]
#define Cc 16
#define Gg 8192
#define Ss 8
#define Ll 3
#define Bb 32

#define ZS 4               // b-oct slices: slice z holds b = 8z .. 8z+7 (bf16)
#define THREADS 512

// --- async global->LDS, 16 B per lane; LDS base must be wave-uniform.
__device__ __forceinline__ void async_load16(const void* gsrc, void* lds) {
    uint32_t l32 = (uint32_t)__builtin_amdgcn_readfirstlane((uint32_t)(uintptr_t)lds);
    __builtin_amdgcn_global_load_lds(
        (const __attribute__((address_space(1))) uint32_t*)(uintptr_t)gsrc,
        (__attribute__((address_space(3))) uint32_t*)(uintptr_t)l32,
        16, 0, 0);
}

// f32 -> bf16 bits, round-to-nearest-even (x in [0,1): no NaN/inf concerns).
__device__ __forceinline__ uint32_t f2bf(float f) {
    uint32_t u = __float_as_uint(f);
    return (u + 0x7fffu + ((u >> 16) & 1u)) >> 16;
}

// --- Kernel A1: pack int32 indices -> uint16 (halves the idx stream).
__global__ __launch_bounds__(256) void pack_idx(const int* __restrict__ I,
                                                ushort* __restrict__ I16) {
    int t = blockIdx.x * 256 + threadIdx.x;        // over C*G*S*L/4
    int4 v = ((const int4*)I)[t];
    ushort4 o = { (ushort)v.x, (ushort)v.y, (ushort)v.z, (ushort)v.w };
    ((ushort4*)I16)[t] = o;
}

// --- Kernel A2: xh[z][g] = uint4 of 8 bf16 = x[8z+0..7][g]. 512 KB total.
__global__ __launch_bounds__(256) void build_xh(const float* __restrict__ x,
                                                uint4* __restrict__ xh) {
    int t = blockIdx.x * 256 + threadIdx.x;        // over ZS*Gg
    int z = t >> 13;
    int g = t & (Gg - 1);
    uint32_t w[4];
    #pragma unroll
    for (int j = 0; j < 4; ++j) {
        uint32_t lo = f2bf(x[(size_t)(8 * z + 2 * j) * Gg + g]);      // coalesced in g
        uint32_t hi = f2bf(x[(size_t)(8 * z + 2 * j + 1) * Gg + g]);
        w[j] = lo | (hi << 16);
    }
    xh[t] = make_uint4(w[0], w[1], w[2], w[3]);    // coalesced 16 B
}

// --- Kernel B: one thread per (c,g) per slice; 8 b's per thread via one
// random ds_read_b128 per index. One stage + ONE barrier per block, no loop
// barriers, stores outside any drained region (R5's failure mode removed).
__global__ __launch_bounds__(THREADS) void clause_bf16(const uint4* __restrict__ xh,
                                                       const ushort* __restrict__ I16,
                                                       float* __restrict__ out) {
    __shared__ uint4 xl[Gg];                       // 128 KB: all G for 8 b's
    const int tid = threadIdx.x;
    const int z = blockIdx.y;
    const int flat = blockIdx.x * THREADS + tid;
    const int c = flat >> 13;                      // block-uniform
    const int g = flat & (Gg - 1);                 // 64 consecutive g per wave

    // Stage slice z: 8 waves x 16 KB, 16 async 1 KB chunks each.
    {
        const char* gs = (const char*)(xh + (size_t)z * Gg);
        char* ls = (char*)xl;
        const int lane = tid & 63;
        const int w = tid >> 6;                    // wave-uniform
        #pragma unroll
        for (int i = 0; i < 16; ++i) {
            int off = ((w << 4) | i) << 10;        // (w*16+i)*1024 B
            async_load16(gs + off + lane * 16, ls + off);
        }
    }

    // Idx loads (24 ushorts = 3 x uint4, 48 B-aligned offset) overlap staging.
    const uint4* ip = (const uint4*)(I16 + (size_t)(c * Gg + g) * (Ss * Ll));
    uint4 i0 = ip[0], i1 = ip[1], i2 = ip[2];

    __syncthreads();                               // drains staging (and idx)

    uint32_t wd[12] = {i0.x, i0.y, i0.z, i0.w, i1.x, i1.y, i1.z, i1.w,
                       i2.x, i2.y, i2.z, i2.w};
    // 24 independent random ds_read_b128 gathers, all in flight (VGPR-rich:
    // LDS caps occupancy at 1 block/CU, so ~250 VGPRs are free).
    uint4 v[Ss * Ll];
    #pragma unroll
    for (int k = 0; k < Ss * Ll; ++k) {
        uint32_t idx = (k & 1) ? (wd[k >> 1] >> 16) : (wd[k >> 1] & 0xffffu);
        v[k] = xl[idx];
    }

    float acc[8] = {0.f, 0.f, 0.f, 0.f, 0.f, 0.f, 0.f, 0.f};
    #pragma unroll
    for (int s = 0; s < Ss; ++s) {
        const uint4 a = v[3 * s], b = v[3 * s + 1], d = v[3 * s + 2];
        const uint32_t* ua = &a.x;
        const uint32_t* ub = &b.x;
        const uint32_t* ud = &d.x;
        #pragma unroll
        for (int j = 0; j < 4; ++j) {
            float a0 = __uint_as_float(ua[j] << 16);
            float a1 = __uint_as_float(ua[j] & 0xffff0000u);
            float b0 = __uint_as_float(ub[j] << 16);
            float b1 = __uint_as_float(ub[j] & 0xffff0000u);
            float d0 = __uint_as_float(ud[j] << 16);
            float d1 = __uint_as_float(ud[j] & 0xffff0000u);
            acc[2 * j]     += a0 * b0 * d0;
            acc[2 * j + 1] += a1 * b1 * d1;
        }
    }

    // Stores: b = 8z+j; lanes span 64 consecutive g -> 256 B coalesced runs.
    float* op = out + ((size_t)(c * Bb + z * 8)) * Gg + g;
    #pragma unroll
    for (int j = 0; j < 8; ++j)
        op[(size_t)j * Gg] = acc[j];
}

// --- Fallback (ws too small): direct global gather; slow but correct.
__global__ __launch_bounds__(256) void clause_kernel_direct(const float* __restrict__ x,
                                                            const int* __restrict__ I,
                                                            float* __restrict__ out) {
    const int tid = threadIdx.x;
    const int b = tid & 31;
    const int j = tid >> 5;
    const int g = blockIdx.x * 8 + j;
    const int c = blockIdx.y;

    const int* Icg = I + (size_t)(c * Gg + g) * (Ss * Ll);
    float sum = 0.f;
    #pragma unroll
    for (int s = 0; s < Ss; ++s) {
        float p0 = x[(size_t)b * Gg + Icg[3 * s + 0]];
        float p1 = x[(size_t)b * Gg + Icg[3 * s + 1]];
        float p2 = x[(size_t)b * Gg + Icg[3 * s + 2]];
        sum += p0 * p1 * p2;
    }
    out[(size_t)(c * Bb + b) * Gg + g] = sum;
}

extern "C" void kernel_launch(void* const* d_in, const int* in_sizes, int n_in,
                              void* d_out, int out_size, void* d_ws, size_t ws_size,
                              hipStream_t stream) {
    const float* x = (const float*)d_in[0];
    const int* I = (const int*)d_in[1];
    float* out = (float*)d_out;

    const size_t nIdx = (size_t)Cc * Gg * Ss * Ll;          // 3.15M
    const size_t xh_bytes = (size_t)ZS * Gg * sizeof(uint4); // 512 KB
    const size_t i16_bytes = nIdx * sizeof(ushort);          // 6.3 MB

    if (ws_size >= xh_bytes + i16_bytes) {
        uint4* xh = (uint4*)d_ws;
        ushort* I16 = (ushort*)((char*)d_ws + xh_bytes);
        pack_idx<<<(int)(nIdx / 4 / 256), 256, 0, stream>>>(I, I16);
        build_xh<<<(ZS * Gg) / 256, 256, 0, stream>>>(x, xh);
        clause_bf16<<<dim3((Cc * Gg) / THREADS, ZS), THREADS, 0, stream>>>(xh, I16, out);
    } else {
        clause_kernel_direct<<<dim3(Gg / 8, Cc), 256, 0, stream>>>(x, I, out);
    }
}

// Round 7
// 84.552 us; speedup vs baseline: 1.0824x; 1.0617x over previous
//
#include <hip/hip_runtime.h>
#include <hip/hip_fp16.h>
#include <stdint.h>

// out[c,b,g] = sum_{s<8} prod_{l<3} x[b, I[c,g,s,l]]
#define Cc 16
#define Gg 8192
#define Ss 8
#define Ll 3
#define Bb 32

#define ZS 4               // b-oct slices (f16): slice z holds b = 8z .. 8z+7
#define THREADS 512
#define ITERS 2            // (c,g) pairs per thread per block -> amortize stage

// --- async global->LDS, 16 B per lane; LDS base must be wave-uniform.
__device__ __forceinline__ void async_load16(const void* gsrc, void* lds) {
    uint32_t l32 = (uint32_t)__builtin_amdgcn_readfirstlane((uint32_t)(uintptr_t)lds);
    __builtin_amdgcn_global_load_lds(
        (const __attribute__((address_space(1))) uint32_t*)(uintptr_t)gsrc,
        (__attribute__((address_space(3))) uint32_t*)(uintptr_t)l32,
        16, 0, 0);
}

// --- Kernel A1: pack int32 indices -> uint16 (halves the per-slice idx stream).
__global__ __launch_bounds__(256) void pack_idx(const int* __restrict__ I,
                                                ushort* __restrict__ I16) {
    int t = blockIdx.x * 256 + threadIdx.x;        // over C*G*S*L/4
    int4 v = ((const int4*)I)[t];
    ushort4 o = { (ushort)v.x, (ushort)v.y, (ushort)v.z, (ushort)v.w };
    ((ushort4*)I16)[t] = o;
}

// --- Kernel A2: xh[z][g] = uint4 of 8 f16 = x[8z+0..7][g]. 512 KB total.
__global__ __launch_bounds__(256) void build_xh(const float* __restrict__ x,
                                                uint4* __restrict__ xh) {
    int t = blockIdx.x * 256 + threadIdx.x;        // over ZS*Gg
    int z = t >> 13;
    int g = t & (Gg - 1);
    uint32_t w[4];
    #pragma unroll
    for (int j = 0; j < 4; ++j) {
        __half2 h = __floats2half2_rn(x[(size_t)(8 * z + 2 * j) * Gg + g],
                                      x[(size_t)(8 * z + 2 * j + 1) * Gg + g]);
        w[j] = *(const uint32_t*)&h;
    }
    xh[t] = make_uint4(w[0], w[1], w[2], w[3]);
}

// --- Kernel B: stage one f16-oct slice (128 KB, all G) ONCE per block, then
// each thread evaluates ITERS (c,g) clauses against it. One barrier total;
// DS-gather work per block (384 b128 instrs) >> stage cost (R6's failure was
// stage ~= compute with nothing overlapping at 1 block/CU).
__global__ __launch_bounds__(THREADS) void clause_f16(const uint4* __restrict__ xh,
                                                      const ushort* __restrict__ I16,
                                                      float* __restrict__ out) {
    __shared__ uint4 xl[Gg];                       // 128 KB
    const int tid = threadIdx.x;
    const int z = blockIdx.y;
    // 8 blocks per c (8 * 1024 = 8192 g): c block-uniform, g-runs contiguous.
    const int c = blockIdx.x >> 3;
    const int gbase = (blockIdx.x & 7) * (THREADS * ITERS);

    // Stage slice z: 8 waves x 16 async 1 KB chunks.
    {
        const char* gs = (const char*)(xh + (size_t)z * Gg);
        char* ls = (char*)xl;
        const int lane = tid & 63;
        const int w = tid >> 6;                    // wave-uniform
        #pragma unroll
        for (int i = 0; i < 16; ++i) {
            int off = ((w << 4) | i) << 10;        // (w*16+i)*1024 B
            async_load16(gs + off + lane * 16, ls + off);
        }
    }

    // Prefetch BOTH iterations' indices before the barrier (overlaps staging).
    uint4 iq[ITERS][3];
    #pragma unroll
    for (int it = 0; it < ITERS; ++it) {
        int g = gbase + it * THREADS + tid;
        const uint4* ip = (const uint4*)(I16 + ((size_t)c * Gg + g) * (Ss * Ll));
        iq[it][0] = ip[0]; iq[it][1] = ip[1]; iq[it][2] = ip[2];
    }

    __syncthreads();                               // the ONE barrier (drains stage)

    #pragma unroll
    for (int it = 0; it < ITERS; ++it) {
        const int g = gbase + it * THREADS + tid;  // 64 consecutive g per wave
        uint32_t wd[12] = {iq[it][0].x, iq[it][0].y, iq[it][0].z, iq[it][0].w,
                           iq[it][1].x, iq[it][1].y, iq[it][1].z, iq[it][1].w,
                           iq[it][2].x, iq[it][2].y, iq[it][2].z, iq[it][2].w};

        // 24 independent random ds_read_b128 gathers, all in flight.
        uint4 v[Ss * Ll];
        #pragma unroll
        for (int k = 0; k < Ss * Ll; ++k) {
            uint32_t idx = (k & 1) ? (wd[k >> 1] >> 16) : (wd[k >> 1] & 0xffffu);
            v[k] = xl[idx];
        }

        float acc[8] = {0.f, 0.f, 0.f, 0.f, 0.f, 0.f, 0.f, 0.f};
        #pragma unroll
        for (int s = 0; s < Ss; ++s) {
            const __half2* a = (const __half2*)&v[3 * s];
            const __half2* b = (const __half2*)&v[3 * s + 1];
            const __half2* d = (const __half2*)&v[3 * s + 2];
            #pragma unroll
            for (int j = 0; j < 4; ++j) {
                __half2 p = __hmul2(__hmul2(a[j], b[j]), d[j]);  // v_pk_mul_f16 x2
                float2 pf = __half22float2(p);
                acc[2 * j]     += pf.x;
                acc[2 * j + 1] += pf.y;
            }
        }

        // b = 8z+j; lanes span 64 consecutive g -> 256 B coalesced runs.
        float* op = out + ((size_t)(c * Bb + 8 * z)) * Gg + g;
        #pragma unroll
        for (int j = 0; j < 8; ++j)
            op[(size_t)j * Gg] = acc[j];
    }
}

// --- Fallback (ws too small): direct global gather; slow but correct.
__global__ __launch_bounds__(256) void clause_kernel_direct(const float* __restrict__ x,
                                                            const int* __restrict__ I,
                                                            float* __restrict__ out) {
    const int tid = threadIdx.x;
    const int b = tid & 31;
    const int j = tid >> 5;
    const int g = blockIdx.x * 8 + j;
    const int c = blockIdx.y;

    const int* Icg = I + (size_t)(c * Gg + g) * (Ss * Ll);
    float sum = 0.f;
    #pragma unroll
    for (int s = 0; s < Ss; ++s) {
        float p0 = x[(size_t)b * Gg + Icg[3 * s + 0]];
        float p1 = x[(size_t)b * Gg + Icg[3 * s + 1]];
        float p2 = x[(size_t)b * Gg + Icg[3 * s + 2]];
        sum += p0 * p1 * p2;
    }
    out[(size_t)(c * Bb + b) * Gg + g] = sum;
}

extern "C" void kernel_launch(void* const* d_in, const int* in_sizes, int n_in,
                              void* d_out, int out_size, void* d_ws, size_t ws_size,
                              hipStream_t stream) {
    const float* x = (const float*)d_in[0];
    const int* I = (const int*)d_in[1];
    float* out = (float*)d_out;

    const size_t nIdx = (size_t)Cc * Gg * Ss * Ll;           // 3.15M
    const size_t xh_bytes = (size_t)ZS * Gg * sizeof(uint4);  // 512 KB
    const size_t i16_bytes = nIdx * sizeof(ushort);           // 6.3 MB

    if (ws_size >= xh_bytes + i16_bytes) {
        uint4* xh = (uint4*)d_ws;
        ushort* I16 = (ushort*)((char*)d_ws + xh_bytes);
        pack_idx<<<(int)(nIdx / 4 / 256), 256, 0, stream>>>(I, I16);
        build_xh<<<(ZS * Gg) / 256, 256, 0, stream>>>(x, xh);
        clause_f16<<<dim3((Cc * Gg) / (THREADS * ITERS), ZS), THREADS, 0, stream>>>(xh, I16, out);
    } else {
        clause_kernel_direct<<<dim3(Gg / 8, Cc), 256, 0, stream>>>(x, I, out);
    }
}

// Round 8
// 82.764 us; speedup vs baseline: 1.1058x; 1.0216x over previous
//
#include <hip/hip_runtime.h>
#include <hip/hip_fp16.h>
#include <stdint.h>

// out[c,b,g] = sum_{s<8} prod_{l<3} x[b, I[c,g,s,l]]
#define Cc 16
#define Gg 8192
#define Ss 8
#define Ll 3
#define Bb 32

#define ZS 4               // b-oct slices (f16): slice z holds b = 8z .. 8z+7
#define THREADS 512
#define ITERS 2            // (c,g) per thread per block

// --- async global->LDS, 16 B per lane; LDS base must be wave-uniform.
__device__ __forceinline__ void async_load16(const void* gsrc, void* lds) {
    uint32_t l32 = (uint32_t)__builtin_amdgcn_readfirstlane((uint32_t)(uintptr_t)lds);
    __builtin_amdgcn_global_load_lds(
        (const __attribute__((address_space(1))) uint32_t*)(uintptr_t)gsrc,
        (__attribute__((address_space(3))) uint32_t*)(uintptr_t)l32,
        16, 0, 0);
}

// --- Kernel A: xh[z][g] = 8 f16 (b = 8z..8z+7), two 8 B halves SWAPPED when
// s(g) = (g>>3)&1. Reader undoes the swap in the ADDRESS (a0 = 2g|s, a1 = a0^1),
// so dword-pass banks become (4(g&7) + 2s + k): 16 banks per pass instead of 8
// -> breaks the quad-bank correlation that made random b128 cost ~90 cyc (R7).
__global__ __launch_bounds__(256) void build_xh(const float* __restrict__ x,
                                                uint4* __restrict__ xh) {
    int t = blockIdx.x * 256 + threadIdx.x;        // over ZS*Gg
    int z = t >> 13;
    int g = t & (Gg - 1);
    uint32_t d[4];
    #pragma unroll
    for (int j = 0; j < 4; ++j) {
        __half2 h = __floats2half2_rn(x[(size_t)(8 * z + 2 * j) * Gg + g],
                                      x[(size_t)(8 * z + 2 * j + 1) * Gg + g]);
        d[j] = *(const uint32_t*)&h;
    }
    uint32_t s = (g >> 3) & 1u;
    xh[t] = s ? make_uint4(d[2], d[3], d[0], d[1])
              : make_uint4(d[0], d[1], d[2], d[3]);
}

// Evaluate one (c,g): 24 indices in q[6], gathers from the swizzled LDS image.
__device__ __forceinline__ void clause_eval(const uint2* __restrict__ xl2,
                                            const int4 q[6], float acc[8]) {
    int idx[Ss * Ll] = {q[0].x, q[0].y, q[0].z, q[0].w, q[1].x, q[1].y, q[1].z, q[1].w,
                        q[2].x, q[2].y, q[2].z, q[2].w, q[3].x, q[3].y, q[3].z, q[3].w,
                        q[4].x, q[4].y, q[4].z, q[4].w, q[5].x, q[5].y, q[5].z, q[5].w};
    uint2 r0[Ss * Ll], r1[Ss * Ll];
    #pragma unroll
    for (int k = 0; k < Ss * Ll; ++k) {            // 48 independent ds_read_b64
        uint32_t u = (uint32_t)idx[k];
        uint32_t a0 = (u << 1) | ((u >> 3) & 1u);  // swizzle undone by address
        r0[k] = xl2[a0];                           // b 0..3 (f16 pairs)
        r1[k] = xl2[a0 ^ 1u];                      // b 4..7
    }
    #pragma unroll
    for (int s = 0; s < Ss; ++s) {
        const int k0 = 3 * s, k1 = 3 * s + 1, k2 = 3 * s + 2;
        const uint32_t pa[4] = {r0[k0].x, r0[k0].y, r1[k0].x, r1[k0].y};
        const uint32_t pb[4] = {r0[k1].x, r0[k1].y, r1[k1].x, r1[k1].y};
        const uint32_t pd[4] = {r0[k2].x, r0[k2].y, r1[k2].x, r1[k2].y};
        #pragma unroll
        for (int j = 0; j < 4; ++j) {
            __half2 a = *(const __half2*)&pa[j];
            __half2 b = *(const __half2*)&pb[j];
            __half2 d = *(const __half2*)&pd[j];
            __half2 p = __hmul2(__hmul2(a, b), d);   // v_pk_mul_f16 x2
            float2 pf = __half22float2(p);
            acc[2 * j] += pf.x;
            acc[2 * j + 1] += pf.y;
        }
    }
}

// --- Kernel B: stage one f16-oct slice (128 KB, all G) once per block; each
// thread evaluates ITERS (c,g) clauses with 2xb64 swizzled gathers.
__global__ __launch_bounds__(THREADS) void clause_f16(const uint4* __restrict__ xh,
                                                      const int* __restrict__ I,
                                                      float* __restrict__ out) {
    __shared__ uint4 xl[Gg];                       // 128 KB
    const int tid = threadIdx.x;
    const int z = blockIdx.y;
    const int c = blockIdx.x >> 3;                 // 8 blocks per c
    const int gbase = (blockIdx.x & 7) * (THREADS * ITERS);

    // Stage slice z: 8 waves x 16 async 1 KB chunks (validated R6/R7 pattern).
    {
        const char* gs = (const char*)(xh + (size_t)z * Gg);
        char* ls = (char*)xl;
        const int lane = tid & 63;
        const int w = tid >> 6;                    // wave-uniform
        #pragma unroll
        for (int i = 0; i < 16; ++i) {
            int off = ((w << 4) | i) << 10;
            async_load16(gs + off + lane * 16, ls + off);
        }
    }

    // Prefetch both iterations' raw int32 indices (overlaps staging; vmcnt path).
    const int g0 = gbase + tid;
    const int g1 = gbase + THREADS + tid;
    const int4* ip0 = (const int4*)(I + ((size_t)c * Gg + g0) * (Ss * Ll));
    const int4* ip1 = (const int4*)(I + ((size_t)c * Gg + g1) * (Ss * Ll));
    int4 q0[6], q1[6];
    #pragma unroll
    for (int k = 0; k < 6; ++k) q0[k] = ip0[k];
    #pragma unroll
    for (int k = 0; k < 6; ++k) q1[k] = ip1[k];

    __syncthreads();                               // the ONE barrier (drains stage)

    const uint2* xl2 = (const uint2*)xl;
    float* opb = out + ((size_t)(c * Bb + 8 * z)) * Gg;

    {
        float acc[8] = {0, 0, 0, 0, 0, 0, 0, 0};
        clause_eval(xl2, q0, acc);
        #pragma unroll
        for (int j = 0; j < 8; ++j)                // 64 consecutive g -> coalesced
            opb[(size_t)j * Gg + g0] = acc[j];
    }
    {
        float acc[8] = {0, 0, 0, 0, 0, 0, 0, 0};
        clause_eval(xl2, q1, acc);
        #pragma unroll
        for (int j = 0; j < 8; ++j)
            opb[(size_t)j * Gg + g1] = acc[j];
    }
}

// --- Fallback (ws too small): direct global gather; slow but correct.
__global__ __launch_bounds__(256) void clause_kernel_direct(const float* __restrict__ x,
                                                            const int* __restrict__ I,
                                                            float* __restrict__ out) {
    const int tid = threadIdx.x;
    const int b = tid & 31;
    const int j = tid >> 5;
    const int g = blockIdx.x * 8 + j;
    const int c = blockIdx.y;

    const int* Icg = I + (size_t)(c * Gg + g) * (Ss * Ll);
    float sum = 0.f;
    #pragma unroll
    for (int s = 0; s < Ss; ++s) {
        float p0 = x[(size_t)b * Gg + Icg[3 * s + 0]];
        float p1 = x[(size_t)b * Gg + Icg[3 * s + 1]];
        float p2 = x[(size_t)b * Gg + Icg[3 * s + 2]];
        sum += p0 * p1 * p2;
    }
    out[(size_t)(c * Bb + b) * Gg + g] = sum;
}

extern "C" void kernel_launch(void* const* d_in, const int* in_sizes, int n_in,
                              void* d_out, int out_size, void* d_ws, size_t ws_size,
                              hipStream_t stream) {
    const float* x = (const float*)d_in[0];
    const int* I = (const int*)d_in[1];
    float* out = (float*)d_out;

    const size_t xh_bytes = (size_t)ZS * Gg * sizeof(uint4);  // 512 KB

    if (ws_size >= xh_bytes) {
        uint4* xh = (uint4*)d_ws;
        build_xh<<<(ZS * Gg) / 256, 256, 0, stream>>>(x, xh);
        clause_f16<<<dim3((Cc * Gg) / (THREADS * ITERS), ZS), THREADS, 0, stream>>>(xh, I, out);
    } else {
        clause_kernel_direct<<<dim3(Gg / 8, Cc), 256, 0, stream>>>(x, I, out);
    }
}